// Round 5
// baseline (1520.424 us; speedup 1.0000x reference)
//
#include <hip/hip_runtime.h>
#include <stdint.h>
#include <math.h>

#define TT 1024
#define FF 32
#define HH 64
#define CSTR 176   // f16 per B-column

typedef unsigned int u32;
typedef _Float16 f16;
typedef __attribute__((ext_vector_type(8))) _Float16 half8;  // 8 fp16 = 4 VGPRs (MFMA A/B frag)
typedef __attribute__((ext_vector_type(4))) float v4f;       // MFMA C/D frag

// hardware-exp2/rcp nonlinearities (v_exp_f32 + v_rcp_f32, ~1e-6 abs err)
__device__ __forceinline__ float fsig(float x) {
    return __builtin_amdgcn_rcpf(1.f + __builtin_amdgcn_exp2f(-1.44269504088896341f * x));
}
__device__ __forceinline__ float ftanh(float x) {
    return 2.f * __builtin_amdgcn_rcpf(1.f + __builtin_amdgcn_exp2f(-2.88539008177792681f * x)) - 1.f;
}

// load 8 consecutive fp32 -> fp16 octet (RNE), for A-fragment prep
__device__ __forceinline__ half8 ld8h(const float* p) {
    float4 a = *(const float4*)p, b = *(const float4*)(p + 4);
    half8 r;
    r[0] = (f16)a.x; r[1] = (f16)a.y; r[2] = (f16)a.z; r[3] = (f16)a.w;
    r[4] = (f16)b.x; r[5] = (f16)b.y; r[6] = (f16)b.z; r[7] = (f16)b.w;
    return r;
}

// lane n <-> n^1 pair sum via DPP quad_perm [1,0,3,2]
__device__ __forceinline__ float pairsum(float v) {
    int t = __builtin_amdgcn_update_dpp(0, __float_as_int(v), 0xB1, 0xF, 0xF, true);
    return v + __int_as_float(t);
}

// Round-5: 2 sequences/block (idle MFMA columns) at 8 waves / 512 threads.
//  r4 post-mortem: kernel is SIMD-issue-bound (MFMA 37% + VALU 54% = 91%);
//  biggest consumer is MFMA issue with 14/16 output columns unused.
//  r3 (2 seq @ 4 waves, grid 256) failed because it ran 1 wave/SIMD (all
//  dependent-chain latency exposed) and paid a full vmcnt(0) store drain at
//  every __syncthreads. This round keeps 2 waves/SIMD (the proven r2/r4
//  intensity) by using 8 waves, and keeps the lgkm-only raw barrier.
//  - 24 tiles over 8 waves = 3 tiles/wave = 9 MFMAs serving BOTH seqs:
//    per-seq-step MFMA issue and barrier count HALVE vs r4.
//  - B cols (mod 4): col c = seq (c>>1)&1, hi/lo c&1. K layout per col:
//    [h_enc(0..63) | x(64..95, hi cols of each seq) | h_dec(96..127)].
//  - Pair p=n>>1: seq p&1, slot p>>1; slot<3 -> tile w*3+slot, unit tile*4+q,
//    one unit-update per pair (2-deep select chain). slot==3 lanes stage x.
//  - hi/lo reduce via DPP quad_perm (lane n <-> n^1, same seq).
//  - grid 256 = 1 block/CU; deferred x prefetch; one lgkm-only barrier/step.

__global__ __launch_bounds__(512, 2)
void lstm_ae_mfma(const float* __restrict__ x,
                  const float* __restrict__ ewih, const float* __restrict__ ewhh,
                  const float* __restrict__ ebih, const float* __restrict__ ebhh,
                  const float* __restrict__ dwih, const float* __restrict__ dwhh,
                  const float* __restrict__ dbih, const float* __restrict__ dbhh,
                  float* __restrict__ out)
{
    const int b2 = blockIdx.x;          // sequences 2*b2, 2*b2+1
    const int t = threadIdx.x;
    const int w = t >> 6;               // wave 0..7
    const int l = t & 63;
    const int q = l >> 4;               // quad: A/B k-group, D row-group
    const int n = l & 15;               // A row-in-tile / B+D column

    __shared__ __align__(16) f16 Bst[2][4][CSTR];    // [buf][col][K+pad]
    __shared__ __align__(16) float xst[2][2][2048];  // [seq][chunk parity][64 x 32]

    // ---- persistent A fragments: wave w owns tiles w*3 .. w*3+2 ----
    half8 af[3][3];
#pragma unroll
    for (int i = 0; i < 3; ++i) {
        int tile = w * 3 + i;
        if (tile < 16) {
            int r = (n & 3) * 64 + tile * 4 + (n >> 2);          // enc W row
            af[i][0] = ld8h(ewhh + r * 64 + q * 8);              // k 0..31  (h_enc)
            af[i][1] = ld8h(ewhh + r * 64 + 32 + q * 8);         // k 32..63 (h_enc)
            af[i][2] = ld8h(ewih + r * 32 + q * 8);              // k 64..95 (x)
        } else {
            int r = (n & 3) * 32 + (tile - 16) * 4 + (n >> 2);   // dec V row
            af[i][0] = ld8h(dwih + r * 64 + q * 8);              // k 0..31  (h_enc)
            af[i][1] = ld8h(dwih + r * 64 + 32 + q * 8);         // k 32..63 (h_enc)
            af[i][2] = ld8h(dwhh + r * 32 + q * 8);              // k 96..127 (h_dec)
        }
    }

    // ---- lane roles: pair p=n>>1: seq p&1, slot p>>1 ----
    const int pr   = n >> 1;
    const int sq   = pr & 1;
    const int slot = pr >> 1;                        // 0..3 (3 = x-stager)
    const bool act = (slot < 3);
    const int T1   = w * 3 + (act ? slot : 0);
    const bool e1  = (T1 < 16);
    const int u1i  = e1 ? T1 * 4 + q : (T1 - 16) * 4 + q;
    const int wk1  = (sq * 2 + (n & 1)) * CSTR + (e1 ? u1i : 96 + u1i);

    float b0 = 0.f, b1 = 0.f, b2b = 0.f, b3 = 0.f, c1 = 0.f;
    if (act) {
        if (e1) {
            b0  = ebih[u1i]       + ebhh[u1i];
            b1  = ebih[64 + u1i]  + ebhh[64 + u1i];
            b2b = ebih[128 + u1i] + ebhh[128 + u1i];
            b3  = ebih[192 + u1i] + ebhh[192 + u1i];
        } else {
            b0  = dbih[u1i]      + dbhh[u1i];
            b1  = dbih[32 + u1i] + dbhh[32 + u1i];
            b2b = dbih[64 + u1i] + dbhh[64 + u1i];
            b3  = dbih[96 + u1i] + dbhh[96 + u1i];
        }
    }

    // ---- prologue: zero Bst, stage x chunk 0 (both seqs), x[0] into buf0 ----
    { u32* bz = (u32*)&Bst[0][0][0]; for (int i2 = t; i2 < 2 * 4 * CSTR / 2; i2 += 512) bz[i2] = 0u; }
    const float* xb0 = x + (size_t)(2 * b2) * TT * FF;
    const float* xb1 = xb0 + TT * FF;
    {
        const int ts = t >> 8;          // seq this thread stages
        const int ti = t & 255;
        const float* xbm = ts ? xb1 : xb0;
        *(float4*)&xst[ts][0][ti * 8]     = *(const float4*)(xbm + ti * 8);
        *(float4*)&xst[ts][0][ti * 8 + 4] = *(const float4*)(xbm + ti * 8 + 4);
    }
    __syncthreads();
    if (t < 32)       Bst[0][0][64 + t]        = (f16)xst[0][0][t];
    else if (t < 64)  Bst[0][2][64 + (t - 32)] = (f16)xst[1][0][t - 32];
    __syncthreads();

    float* outp = out + (size_t)(2 * b2 + sq) * TT * FF;

    for (int tt = 0; tt <= TT; ++tt) {
        const int p = tt & 1;

        // x chunk prefetch: issue global loads now, LDS write deferred to loop end
        float4 px0, px1;
        const int cn = (tt >> 6) + 1;
        const bool pf = ((tt & 63) == 0) && (cn < 16);
        if (pf) {
            const float* xbm = (t >> 8) ? xb1 : xb0;
            px0 = *(const float4*)(xbm + cn * 2048 + (t & 255) * 8);
            px1 = *(const float4*)(xbm + cn * 2048 + (t & 255) * 8 + 4);
        }

        // ---- B fragments: col = n&3 (4 lanes/address broadcast) ----
        const f16* Bp = &Bst[p][0][0];
        const int cb = (n & 3) * CSTR + q * 8;
        half8 bf0 = *(const half8*)(Bp + cb);
        half8 bf1 = *(const half8*)(Bp + cb + 32);
        half8 bf2 = *(const half8*)(Bp + cb + 64);
        half8 bf3 = *(const half8*)(Bp + cb + 96);

        v4f zero = {0.f, 0.f, 0.f, 0.f};
        v4f acc[3];
#pragma unroll
        for (int i = 0; i < 3; ++i)
            acc[i] = __builtin_amdgcn_mfma_f32_16x16x32_f16(af[i][2], (w * 3 + i < 16) ? bf2 : bf3,
                                                            zero, 0, 0, 0);
#pragma unroll
        for (int i = 0; i < 3; ++i)
            acc[i] = __builtin_amdgcn_mfma_f32_16x16x32_f16(af[i][0], bf0, acc[i], 0, 0, 0);
#pragma unroll
        for (int i = 0; i < 3; ++i)
            acc[i] = __builtin_amdgcn_mfma_f32_16x16x32_f16(af[i][1], bf1, acc[i], 0, 0, 0);

        // ---- select this pair's tile (2 cndmask sets) ----
        v4f u_ = acc[0];
        if (slot == 1) u_ = acc[1];
        if (slot == 2) u_ = acc[2];

        // ---- hi+lo reduce: lane n <-> n^1 (same seq) ----
        v4f s_;
#pragma unroll
        for (int e = 0; e < 4; ++e) s_[e] = pairsum(u_[e]);

        f16* Bw = &Bst[p ^ 1][0][0];

        // ---- unit update (one unit per active pair) + h write to buf p^1 ----
        if (act && (e1 ? (tt < TT) : (tt >= 1))) {
            float i_ = fsig(s_[0] + b0);
            float f_ = fsig(s_[1] + b1);
            float g_ = ftanh(s_[2] + b2b);
            float o_ = fsig(s_[3] + b3);
            c1 = f_ * c1 + i_ * g_;
            float h = o_ * ftanh(c1);
            f16 hi = (f16)h;
            f16 lo = (f16)(h - (float)hi);
            Bw[wk1] = (n & 1) ? lo : hi;
            if (!e1 && !(n & 1))
                outp[(size_t)(tt - 1) * FF + u1i] = h;
        }
        // ---- x staging for enc step tt+1 (slot-3 even lanes: n=12 seq0, n=14 seq1) ----
        if (n == 12 || n == 14) {
            int st = tt + 1;
            if (st < TT) {
                int sx = (n - 12) >> 1;
                int jj = w * 4 + q;
                Bw[(sx * 2) * CSTR + 64 + jj] = (f16)xst[sx][(st >> 6) & 1][(st & 63) * 32 + jj];
            }
        }

        // deferred x-chunk prefetch write (loads in flight across MFMA + update)
        if (pf) {
            *(float4*)&xst[t >> 8][cn & 1][(t & 255) * 8]     = px0;
            *(float4*)&xst[t >> 8][cn & 1][(t & 255) * 8 + 4] = px1;
        }

        // ---- raw barrier: drain LDS only; out[] stores stay in flight ----
        asm volatile("s_waitcnt lgkmcnt(0)" ::: "memory");
        __builtin_amdgcn_s_barrier();
        __builtin_amdgcn_sched_barrier(0);
    }
}

extern "C" void kernel_launch(void* const* d_in, const int* in_sizes, int n_in,
                              void* d_out, int out_size, void* d_ws, size_t ws_size,
                              hipStream_t stream) {
    (void)in_sizes; (void)n_in; (void)out_size; (void)d_ws; (void)ws_size;
    lstm_ae_mfma<<<256, 512, 0, stream>>>((const float*)d_in[0],
                                          (const float*)d_in[1], (const float*)d_in[2],
                                          (const float*)d_in[3], (const float*)d_in[4],
                                          (const float*)d_in[5], (const float*)d_in[6],
                                          (const float*)d_in[7], (const float*)d_in[8],
                                          (float*)d_out);
}

// Round 6
// 731.332 us; speedup vs baseline: 2.0790x; 2.0790x over previous
//
#include <hip/hip_runtime.h>
#include <stdint.h>
#include <math.h>

#define TT 1024
#define FF 32
#define HH 64

typedef unsigned int u32;
typedef _Float16 f16;
typedef __attribute__((ext_vector_type(8))) _Float16 half8;  // 8 fp16 = 4 VGPRs (MFMA A/B frag)
typedef __attribute__((ext_vector_type(4))) float v4f;       // MFMA C/D frag

#define L2E  1.44269504088896341f   // log2(e)
#define L2E2 2.88539008177792681f   // 2*log2(e)

// pre-scaled-input nonlinearities: input already multiplied by L2E (sig) or
// L2E2 (tanh) via weight/bias folding. v_exp_f32(-x) uses the free neg mod.
__device__ __forceinline__ float fsig_s(float s) {           // sigmoid(s/L2E)
    return __builtin_amdgcn_rcpf(1.f + __builtin_amdgcn_exp2f(-s));
}
__device__ __forceinline__ float ftanh_s(float s) {          // tanh(s/L2E2)
    return 2.f * __builtin_amdgcn_rcpf(1.f + __builtin_amdgcn_exp2f(-s)) - 1.f;
}

// load 8 consecutive fp32, scale, -> fp16 octet (RNE), for A-fragment prep
__device__ __forceinline__ half8 ld8h(const float* p, float sc) {
    float4 a = *(const float4*)p, b = *(const float4*)(p + 4);
    half8 r;
    r[0] = (f16)(a.x * sc); r[1] = (f16)(a.y * sc); r[2] = (f16)(a.z * sc); r[3] = (f16)(a.w * sc);
    r[4] = (f16)(b.x * sc); r[5] = (f16)(b.y * sc); r[6] = (f16)(b.z * sc); r[7] = (f16)(b.w * sc);
    return r;
}

// Round-6 = r4 (741 us proven: 512 blocks x 4 waves, 1 seq/block, 2 indep
// blocks/CU, lgkm-only barrier) + two critical-path shaves:
//  1. MFMA chain reordered bf0 -> bf1 -> bfx: first MFMA now waits only for
//     the FIRST ds_read_b128 return (lgkmcnt(3)) instead of the last
//     (lgkmcnt(0)) -- removes ~2-3 LDS-return latencies from the serial path.
//  2. log2e folded into A fragments + biases at prologue (gate-g rows x
//     2log2e, i/f/o rows x log2e; cell state kept in 2log2e-scaled domain):
//     removes the per-gate input-scaling muls and one dep stage from each
//     transcendental chain, every step.
// r3/r5 lesson (final): barrier-synced waves don't hide each other's serial
// path; only independent co-resident blocks do. 512 x 1-seq blocks (2/CU) is
// the only shape with 2 independent streams/CU -- multi-seq blocks are dead.

__global__ __launch_bounds__(256, 2)
void lstm_ae_mfma(const float* __restrict__ x,
                  const float* __restrict__ ewih, const float* __restrict__ ewhh,
                  const float* __restrict__ ebih, const float* __restrict__ ebhh,
                  const float* __restrict__ dwih, const float* __restrict__ dwhh,
                  const float* __restrict__ dbih, const float* __restrict__ dbhh,
                  float* __restrict__ out)
{
    const int b = blockIdx.x;
    const int t = threadIdx.x;
    const int w = t >> 6;        // wave 0..3
    const int l = t & 63;
    const int q = l >> 4;        // quad: A/B k-group, D row-group
    const int n = l & 15;        // A row-in-tile / B+D column

    __shared__ __align__(16) f16 Bst[2][2][160];     // [buf][col hi/lo][K(128)+pad]
    __shared__ __align__(16) float xst[2][2048];     // x 64-step chunks, fp32, dbuf

    // ---- persistent A fragments (fp32 -> fp16, gate-scaled) ----
    // lane n's A rows are gate (n&3) rows; gate 2 (= g, tanh) scaled by 2log2e,
    // gates i/f/o by log2e. D reg e = gate e picks up exactly factor(e).
    const float sc = ((n & 3) == 2) ? L2E2 : L2E;
    half8 af[6][3];
#pragma unroll
    for (int i = 0; i < 6; ++i) {
        int tile = w * 6 + i;
        if (tile < 16) {
            int r = (n & 3) * 64 + tile * 4 + (n >> 2);          // enc W row
            af[i][0] = ld8h(ewhh + r * 64 + q * 8, sc);          // k 0..31  (h_enc)
            af[i][1] = ld8h(ewhh + r * 64 + 32 + q * 8, sc);     // k 32..63 (h_enc)
            af[i][2] = ld8h(ewih + r * 32 + q * 8, sc);          // k 64..95 (x)
        } else {
            int r = (n & 3) * 32 + (tile - 16) * 4 + (n >> 2);   // dec V row
            af[i][0] = ld8h(dwih + r * 64 + q * 8, sc);          // k 0..31  (h_enc)
            af[i][1] = ld8h(dwih + r * 64 + 32 + q * 8, sc);     // k 32..63 (h_enc)
            af[i][2] = ld8h(dwhh + r * 32 + q * 8, sc);          // k 96..127 (h_dec)
        }
    }

    // ---- lane-pair roles: pair s=n>>1 (<6) owns tile w*6+s; even=hi, odd=lo ----
    const int sel = n >> 1;                          // 0..7
    const bool act = (n < 12);                       // 6 pairs active
    const int tile_s = w * 6 + (sel < 6 ? sel : 0);  // clamped for inactive lanes
    const bool is_enc = (tile_s < 16);
    const int u = is_enc ? (tile_s * 4 + q) : ((tile_s - 16) * 4 + q);

    float b0 = 0.f, b1 = 0.f, b2 = 0.f, b3 = 0.f, c_st = 0.f;
    if (act) {
        if (is_enc) {
            b0 = ebih[u]       + ebhh[u];
            b1 = ebih[64 + u]  + ebhh[64 + u];
            b2 = ebih[128 + u] + ebhh[128 + u];
            b3 = ebih[192 + u] + ebhh[192 + u];
        } else {
            b0 = dbih[u]      + dbhh[u];
            b1 = dbih[32 + u] + dbhh[32 + u];
            b2 = dbih[64 + u] + dbhh[64 + u];
            b3 = dbih[96 + u] + dbhh[96 + u];
        }
    }
    // fold the nonlinearity input scaling into the biases (gate g: 2log2e)
    b0 *= L2E; b1 *= L2E; b2 *= L2E2; b3 *= L2E;

    // ---- prologue: zero both Bst buffers, stage x chunk 0, x[0] into buf0 ----
    { u32* bz = (u32*)&Bst[0][0][0]; for (int i2 = t; i2 < 2 * 2 * 160 / 2; i2 += 256) bz[i2] = 0u; }
    const float* xb = x + (size_t)b * TT * FF;
    *(float4*)&xst[0][t * 8]     = *(const float4*)(xb + t * 8);
    *(float4*)&xst[0][t * 8 + 4] = *(const float4*)(xb + t * 8 + 4);
    __syncthreads();
    if (t >= 96 && t < 128) Bst[0][0][64 + (t - 96)] = (f16)xst[0][t - 96];
    __syncthreads();

    for (int tt = 0; tt <= TT; ++tt) {
        const int p = tt & 1;

        // x chunk prefetch: issue loads now, write LDS just before the barrier
        float4 px0, px1;
        const int cn = (tt >> 6) + 1;
        const bool pf = ((tt & 63) == 0) && (cn < 16);
        if (pf) {
            px0 = *(const float4*)(xb + cn * 2048 + t * 8);
            px1 = *(const float4*)(xb + cn * 2048 + t * 8 + 4);
        }

        // ---- B fragments (col = n&1 replicated, broadcast reads; issue order
        //      bf0,bf1,bf2,bf3 -> returns in order) ----
        const f16* Bp = &Bst[p][0][0];
        const int cb = (n & 1) * 160 + q * 8;
        half8 bf0 = *(const half8*)(Bp + cb);
        half8 bf1 = *(const half8*)(Bp + cb + 32);
        half8 bf2 = *(const half8*)(Bp + cb + 64);
        half8 bf3 = *(const half8*)(Bp + cb + 96);

        v4f zero = {0.f, 0.f, 0.f, 0.f};
        v4f acc[6];
        // stage 1: bf0 (first LDS return) -- MFMAs start at lgkmcnt(3)
#pragma unroll
        for (int i = 0; i < 6; ++i)
            acc[i] = __builtin_amdgcn_mfma_f32_16x16x32_f16(af[i][0], bf0, zero, 0, 0, 0);
        // stage 2: bf1
#pragma unroll
        for (int i = 0; i < 6; ++i)
            acc[i] = __builtin_amdgcn_mfma_f32_16x16x32_f16(af[i][1], bf1, acc[i], 0, 0, 0);
        // stage 3: x (enc tiles) or h_dec (dec tiles)
#pragma unroll
        for (int i = 0; i < 6; ++i)
            acc[i] = __builtin_amdgcn_mfma_f32_16x16x32_f16(af[i][2], (w * 6 + i < 16) ? bf2 : bf3,
                                                            acc[i], 0, 0, 0);

        // ---- select this pair's tile (cndmask chain, static indices) ----
        v4f u_ = acc[0];
#pragma unroll
        for (int i = 1; i < 6; ++i) if (sel == i) u_ = acc[i];

        // ---- hi+lo reduce: lane n <-> n^1 via DPP quad_perm [1,0,3,2] ----
        v4f s_;
#pragma unroll
        for (int e = 0; e < 4; ++e) {
            int tmp = __builtin_amdgcn_update_dpp(0, __float_as_int(u_[e]), 0xB1, 0xF, 0xF, true);
            s_[e] = u_[e] + __int_as_float(tmp);
        }

        // ---- unit update (pre-scaled domain) + h write to buf p^1 ----
        f16* Bw = &Bst[p ^ 1][0][0];
        if (act && (is_enc ? (tt < TT) : (tt >= 1))) {
            float i_ = fsig_s(s_[0] + b0);
            float f_ = fsig_s(s_[1] + b1);
            float g_ = ftanh_s(s_[2] + b2);
            float o_ = fsig_s(s_[3] + b3);
            // c kept in 2log2e-scaled domain so tanh(c) needs no rescale
            c_st = f_ * c_st + L2E2 * (i_ * g_);
            float h = o_ * ftanh_s(c_st);
            f16 hi = (f16)h;
            f16 lo = (f16)(h - (float)hi);
            const int kk = is_enc ? u : (96 + u);
            Bw[(n & 1) * 160 + kk] = (n & 1) ? lo : hi;
            if (!is_enc && !(n & 1))
                out[(size_t)b * TT * FF + (size_t)(tt - 1) * FF + u] = h;
        } else if (n == 12 || n == 13) {        // stage x for enc step tt+1
            int st = tt + 1;
            if (st < TT) {
                int j = w * 8 + q * 2 + (n - 12);
                Bw[64 + j] = (f16)xst[(st >> 6) & 1][(st & 63) * 32 + j];
            }
        }

        // deferred x-chunk prefetch write (loads in flight across MFMA + update)
        if (pf) {
            *(float4*)&xst[cn & 1][t * 8]     = px0;
            *(float4*)&xst[cn & 1][t * 8 + 4] = px1;
        }

        // ---- raw barrier: drain LDS only; out[] stores stay in flight ----
        asm volatile("s_waitcnt lgkmcnt(0)" ::: "memory");
        __builtin_amdgcn_s_barrier();
        __builtin_amdgcn_sched_barrier(0);
    }
}

extern "C" void kernel_launch(void* const* d_in, const int* in_sizes, int n_in,
                              void* d_out, int out_size, void* d_ws, size_t ws_size,
                              hipStream_t stream) {
    (void)in_sizes; (void)n_in; (void)out_size; (void)d_ws; (void)ws_size;
    lstm_ae_mfma<<<512, 256, 0, stream>>>((const float*)d_in[0],
                                          (const float*)d_in[1], (const float*)d_in[2],
                                          (const float*)d_in[3], (const float*)d_in[4],
                                          (const float*)d_in[5], (const float*)d_in[6],
                                          (const float*)d_in[7], (const float*)d_in[8],
                                          (float*)d_out);
}